// Round 3
// baseline (1132.079 us; speedup 1.0000x reference)
//
#include <hip/hip_runtime.h>

// SNN 2-layer LIF forward scan. T=1000, B=8192, I=9, H=96, O=3.
// R3: GRP=32 lanes/batch-element (3 layer-1 units per lane) -> 4096 waves
// (4/SIMD, 2x R2 occupancy). Layer-2 keeps R1/R2's exact reduction tree:
// lane pairs exchange spikes (shfl_xor 1) and redundantly compute the same
// 6-FMA chain, then xor 2,4,8,16 butterfly == R1's xor 1,2,4,8 over 16.
// Bit-identical output to R2. Plain stores (NT stores inflated WRITE_SIZE).

#define T_STEPS 1000
#define BATCH   8192
#define NIN     9
#define HID     96
#define NOUT    3
#define GRP     32
#define UPL     3      // layer-1 units per lane
#define CPL     6      // layer-2 chain length (pair's 6 units)

__device__ __forceinline__ void loadx(float xr[NIN], const float* __restrict__ p) {
    #pragma unroll
    for (int i = 0; i < NIN; ++i) xr[i] = p[i];
}

__global__ __launch_bounds__(256, 4) void snn_fwd_kernel(
    const float* __restrict__ x,    // (T,B,9)
    const float* __restrict__ W1,   // (96,9)
    const float* __restrict__ b1,   // (96)
    const float* __restrict__ W2,   // (3,96)
    const float* __restrict__ b2,   // (3)
    float* __restrict__ out)        // spk2 (T,B,3) then mem2 (T,B,3)
{
    const int tid = blockIdx.x * blockDim.x + threadIdx.x;
    const int li  = tid & (GRP - 1);
    const int b   = tid / GRP;
    const int par = li & 1;                 // pair parity
    const int u0  = li * UPL;               // first layer-1 unit this lane owns
    const int pb  = (li >> 1) * CPL;        // pair's first unit (R1 lane k = li>>1)

    // ---- preload weights into registers ----
    float w1r[UPL][NIN];
    float b1r[UPL];
    float w2r[NOUT][CPL];                   // pair's 6 units (same in both lanes)
    #pragma unroll
    for (int u = 0; u < UPL; ++u) {
        b1r[u] = b1[u0 + u];
        #pragma unroll
        for (int i = 0; i < NIN; ++i)
            w1r[u][i] = W1[(u0 + u) * NIN + i];
    }
    #pragma unroll
    for (int o = 0; o < NOUT; ++o)
        #pragma unroll
        for (int j = 0; j < CPL; ++j)
            w2r[o][j] = W2[o * HID + pb + j];
    const float b2r0 = b2[0], b2r1 = b2[1], b2r2 = b2[2];

    // ---- state ----
    float mem1[UPL], spk1[UPL];
    #pragma unroll
    for (int u = 0; u < UPL; ++u) { mem1[u] = 0.0f; spk1[u] = 0.0f; }
    float m20 = 0.0f, m21 = 0.0f, m22 = 0.0f;
    float s20 = 0.0f, s21 = 0.0f, s22 = 0.0f;

    const float* xrow = x + (size_t)b * NIN;
    const size_t xstride = (size_t)BATCH * NIN;

    const size_t ostride  = (size_t)BATCH * NOUT;
    const size_t mem_base = (size_t)T_STEPS * ostride;
    const size_t obase0   = (size_t)b * NOUT;

    // ---- x prefetch buffers, distance 2 ----
    float x0[NIN], x1[NIN], x2[NIN], x3[NIN];
    loadx(x0, xrow + 0 * xstride);
    loadx(x1, xrow + 1 * xstride);

    #define CLAMP_T(tt) (((tt) < T_STEPS) ? (tt) : (T_STEPS - 1))

    #define STEP(tcur, xr)                                                     \
    do {                                                                       \
        /* layer 1: per-unit ascending-k FMA chain, then +b1 */                \
        float acc[UPL];                                                        \
        _Pragma("unroll")                                                      \
        for (int u = 0; u < UPL; ++u) acc[u] = 0.0f;                           \
        _Pragma("unroll")                                                      \
        for (int i = 0; i < NIN; ++i) {                                        \
            float xi = (xr)[i];                                                \
            _Pragma("unroll")                                                  \
            for (int u = 0; u < UPL; ++u)                                      \
                acc[u] = __builtin_fmaf(xi, w1r[u][i], acc[u]);                \
        }                                                                      \
        /* leaky 1: rst == previous spike (exact identity) */                  \
        _Pragma("unroll")                                                      \
        for (int u = 0; u < UPL; ++u) {                                        \
            float cur = __fadd_rn(acc[u], b1r[u]);                             \
            float m = __fadd_rn(__fmul_rn(0.92f, mem1[u]), cur);               \
            m = __fsub_rn(m, spk1[u]);                                         \
            mem1[u] = m;                                                       \
            spk1[u] = (m > 1.0f) ? 1.0f : 0.0f;                                \
        }                                                                      \
        /* build the pair's 6-spike vector (partner via xor-1 shuffle) */      \
        float spo[UPL];                                                        \
        _Pragma("unroll")                                                      \
        for (int u = 0; u < UPL; ++u) spo[u] = __shfl_xor(spk1[u], 1, GRP);    \
        float spk6[CPL];                                                       \
        _Pragma("unroll")                                                      \
        for (int u = 0; u < UPL; ++u) {                                        \
            spk6[u]       = par ? spo[u]  : spk1[u];                           \
            spk6[u + UPL] = par ? spk1[u] : spo[u];                            \
        }                                                                      \
        /* layer 2: 6-FMA chain (== R1 lane) + xor 2,4,8,16 butterfly */       \
        float p0, p1, p2;                                                      \
        {                                                                      \
            float s = 0.0f;                                                    \
            _Pragma("unroll")                                                  \
            for (int j = 0; j < CPL; ++j)                                      \
                s = __builtin_fmaf(spk6[j], w2r[0][j], s);                     \
            s = __fadd_rn(s, __shfl_xor(s, 2, GRP));                           \
            s = __fadd_rn(s, __shfl_xor(s, 4, GRP));                           \
            s = __fadd_rn(s, __shfl_xor(s, 8, GRP));                           \
            s = __fadd_rn(s, __shfl_xor(s, 16, GRP));                          \
            p0 = s;                                                            \
        }                                                                      \
        {                                                                      \
            float s = 0.0f;                                                    \
            _Pragma("unroll")                                                  \
            for (int j = 0; j < CPL; ++j)                                      \
                s = __builtin_fmaf(spk6[j], w2r[1][j], s);                     \
            s = __fadd_rn(s, __shfl_xor(s, 2, GRP));                           \
            s = __fadd_rn(s, __shfl_xor(s, 4, GRP));                           \
            s = __fadd_rn(s, __shfl_xor(s, 8, GRP));                           \
            s = __fadd_rn(s, __shfl_xor(s, 16, GRP));                          \
            p1 = s;                                                            \
        }                                                                      \
        {                                                                      \
            float s = 0.0f;                                                    \
            _Pragma("unroll")                                                  \
            for (int j = 0; j < CPL; ++j)                                      \
                s = __builtin_fmaf(spk6[j], w2r[2][j], s);                     \
            s = __fadd_rn(s, __shfl_xor(s, 2, GRP));                           \
            s = __fadd_rn(s, __shfl_xor(s, 4, GRP));                           \
            s = __fadd_rn(s, __shfl_xor(s, 8, GRP));                           \
            s = __fadd_rn(s, __shfl_xor(s, 16, GRP));                          \
            p2 = s;                                                            \
        }                                                                      \
        /* leaky 2 (replicated; rst2 == previous spk2) */                      \
        {                                                                      \
            float cur = __fadd_rn(p0, b2r0);                                   \
            float m = __fadd_rn(__fmul_rn(0.92f, m20), cur);                   \
            m = __fsub_rn(m, s20);                                             \
            m20 = m; s20 = (m > 1.0f) ? 1.0f : 0.0f;                           \
        }                                                                      \
        {                                                                      \
            float cur = __fadd_rn(p1, b2r1);                                   \
            float m = __fadd_rn(__fmul_rn(0.92f, m21), cur);                   \
            m = __fsub_rn(m, s21);                                             \
            m21 = m; s21 = (m > 1.0f) ? 1.0f : 0.0f;                           \
        }                                                                      \
        {                                                                      \
            float cur = __fadd_rn(p2, b2r2);                                   \
            float m = __fadd_rn(__fmul_rn(0.92f, m22), cur);                   \
            m = __fsub_rn(m, s22);                                             \
            m22 = m; s22 = (m > 1.0f) ? 1.0f : 0.0f;                           \
        }                                                                      \
        /* store: lanes 0..2 spk2, lanes 3..5 mem2 */                          \
        const size_t ob = (size_t)(tcur) * ostride + obase0;                   \
        if (li < NOUT) {                                                       \
            float v = (li == 0) ? s20 : (li == 1) ? s21 : s22;                 \
            out[ob + li] = v;                                                  \
        } else if (li < 2 * NOUT) {                                            \
            int c = li - NOUT;                                                 \
            float v = (c == 0) ? m20 : (c == 1) ? m21 : m22;                   \
            out[mem_base + ob + c] = v;                                        \
        }                                                                      \
    } while (0)

    for (int t = 0; t < T_STEPS; t += 4) {
        loadx(x2, xrow + (size_t)CLAMP_T(t + 2) * xstride);
        STEP(t, x0);
        loadx(x3, xrow + (size_t)CLAMP_T(t + 3) * xstride);
        STEP(t + 1, x1);
        loadx(x0, xrow + (size_t)CLAMP_T(t + 4) * xstride);
        STEP(t + 2, x2);
        loadx(x1, xrow + (size_t)CLAMP_T(t + 5) * xstride);
        STEP(t + 3, x3);
    }
    #undef STEP
    #undef CLAMP_T
}

extern "C" void kernel_launch(void* const* d_in, const int* in_sizes, int n_in,
                              void* d_out, int out_size, void* d_ws, size_t ws_size,
                              hipStream_t stream) {
    const float* x  = (const float*)d_in[0];
    const float* W1 = (const float*)d_in[1];
    const float* b1 = (const float*)d_in[2];
    const float* W2 = (const float*)d_in[3];
    const float* b2 = (const float*)d_in[4];
    float* out = (float*)d_out;

    const int total_threads = BATCH * GRP;   // 262144
    dim3 block(256);
    dim3 grid(total_threads / 256);          // 1024
    snn_fwd_kernel<<<grid, block, 0, stream>>>(x, W1, b1, W2, b2, out);
}